// Round 1
// baseline (739.524 us; speedup 1.0000x reference)
//
#include <hip/hip_runtime.h>
#include <stdint.h>

#define NN 2048
#define BB 8
#define BN (BB*NN)
#define KK 16
#define EE (BN*KK)
#define HID 128
#define PROJ_D 256

typedef unsigned long long u64;

__device__ __forceinline__ u64 wave_min_u64(u64 v) {
  #pragma unroll
  for (int off = 32; off > 0; off >>= 1) {
    u64 o = __shfl_xor(v, off);
    v = o < v ? o : v;
  }
  return v;
}

// ---------------- kNN: one wave (64 threads) per query node ----------------
__global__ __launch_bounds__(64) void knn_kernel(const float* __restrict__ pos,
                                                 int* __restrict__ nbr) {
  __shared__ float Ps[NN * 3];
  const int q = blockIdx.x;          // global node id
  const int b = q >> 11;             // / NN
  const int i = q & (NN - 1);
  const float* P = pos + (size_t)b * NN * 3;
  const int lane = threadIdx.x;

  for (int t = lane; t < NN * 3 / 4; t += 64)
    ((float4*)Ps)[t] = ((const float4*)P)[t];
  __syncthreads();

  const float xi = Ps[i*3+0], yi = Ps[i*3+1], zi = Ps[i*3+2];

  u64 best[17];
  #pragma unroll
  for (int t = 0; t < 17; t++) best[t] = ~0ull;

  for (int j = lane; j < NN; j += 64) {
    float dx = fabsf(xi - Ps[j*3+0]);
    float dy = fabsf(yi - Ps[j*3+1]);
    float dz = fabsf(zi - Ps[j*3+2]);
    if (dx > 0.5f) dx = 1.0f - dx;
    if (dy > 0.5f) dy = 1.0f - dy;
    if (dz > 0.5f) dz = 1.0f - dz;
    // match numpy fp32 exactly: no FMA contraction, sum order ((x+y)+z)+eps
    float s = __fadd_rn(__fadd_rn(__fadd_rn(__fmul_rn(dx,dx), __fmul_rn(dy,dy)),
                                  __fmul_rn(dz,dz)), 1e-12f);
    float d = __fsqrt_rn(s);
    u64 key = ((u64)__float_as_uint(d) << 32) | (unsigned)j;
    if (key < best[16]) {
      best[16] = key;
      #pragma unroll
      for (int t = 16; t > 0; t--) {   // one bubble pass, static indices only
        u64 a = best[t-1], c = best[t];
        best[t-1] = a < c ? a : c;
        best[t]   = a < c ? c : a;
      }
    }
  }

  int* outp = nbr + (size_t)q * KK;
  #pragma unroll 1
  for (int r = 0; r < KK + 1; r++) {
    u64 h = best[0];
    u64 m = wave_min_u64(h);
    if (r >= 1 && lane == 0) outp[r-1] = b * NN + (int)(m & 0xffffffffu);
    bool pop = (h == m);               // exactly one lane matches (keys unique)
    #pragma unroll
    for (int t = 0; t < 16; t++) best[t] = pop ? best[t+1] : best[t];
    best[16] = pop ? ~0ull : best[16];
  }
}

// ---------------- CSR build ----------------
__global__ __launch_bounds__(256) void count_kernel(const int* __restrict__ nbr,
                                                    int* __restrict__ cnt) {
  int e = blockIdx.x * 256 + threadIdx.x;
  atomicAdd(&cnt[nbr[e]], 1);
}

__global__ __launch_bounds__(256) void scan_kernel(const int* __restrict__ cnt,
                                                   int* __restrict__ row_ptr) {
  __shared__ int ps[256];
  int t = threadIdx.x;
  int base = t * 64;
  int s = 0;
  for (int i = 0; i < 64; i++) s += cnt[base + i];
  ps[t] = s;
  __syncthreads();
  for (int off = 1; off < 256; off <<= 1) {
    int v = 0;
    if (t >= off) v = ps[t - off];
    __syncthreads();
    ps[t] += v;
    __syncthreads();
  }
  int run = t ? ps[t - 1] : 0;
  for (int i = 0; i < 64; i++) { row_ptr[base + i] = run; run += cnt[base + i]; }
  if (t == 255) row_ptr[BN] = run;
}

__global__ __launch_bounds__(256) void fill_kernel(const int* __restrict__ nbr,
                                                   const int* __restrict__ row_ptr,
                                                   int* __restrict__ fill,
                                                   int* __restrict__ col) {
  int e = blockIdx.x * 256 + threadIdx.x;
  int d = nbr[e];
  int srcn = e >> 4;                  // / KK
  int p = row_ptr[d] + atomicAdd(&fill[d], 1);
  col[p] = srcn;
}

// ---------------- encoder layer 0: (BN,5)@(5,128)+relu ----------------
__global__ __launch_bounds__(256) void enc0_kernel(const float* __restrict__ x,
                                                   const float* __restrict__ w0,
                                                   const float* __restrict__ b0,
                                                   float* __restrict__ h) {
  int t = blockIdx.x * 256 + threadIdx.x;
  int m = t >> 5;
  int c = (t & 31) * 4;
  float xv[5];
  #pragma unroll
  for (int d = 0; d < 5; d++) xv[d] = x[m * 5 + d];
  float4 acc = *(const float4*)&b0[c];
  #pragma unroll
  for (int d = 0; d < 5; d++) {
    float4 w = *(const float4*)&w0[d * HID + c];
    acc.x += xv[d] * w.x; acc.y += xv[d] * w.y;
    acc.z += xv[d] * w.z; acc.w += xv[d] * w.w;
  }
  acc.x = fmaxf(acc.x, 0.f); acc.y = fmaxf(acc.y, 0.f);
  acc.z = fmaxf(acc.z, 0.f); acc.w = fmaxf(acc.w, 0.f);
  *(float4*)&h[(size_t)m * HID + c] = acc;
}

// ---------------- generic skinny GEMM: out = act(A@W1 [+ B@W2] + bias) [+ Res]
// block: 64 rows x 128 cols, 256 threads, each thread 8x4 outputs
template<int HASB, int RELU, int HASRES>
__global__ __launch_bounds__(256) void gemm_kernel(
    const float* __restrict__ A, const float* __restrict__ W1,
    const float* __restrict__ Bi, const float* __restrict__ W2,
    const float* __restrict__ bias, const float* __restrict__ Res,
    float* __restrict__ out, int ldW, int ldOut) {
  __shared__ float As[64 * 128];
  __shared__ float Bs[HASB ? 64 * 128 : 4];
  const int m0 = blockIdx.x * 64;
  {
    const float4* Ap = (const float4*)(A + (size_t)m0 * 128);
    const float4* Bp = HASB ? (const float4*)(Bi + (size_t)m0 * 128) : nullptr;
    for (int t = threadIdx.x; t < 64 * 32; t += 256) {
      ((float4*)As)[t] = Ap[t];
      if (HASB) ((float4*)Bs)[t] = Bp[t];
    }
  }
  __syncthreads();
  const int tx = threadIdx.x & 31, ty = threadIdx.x >> 5;
  const int n = blockIdx.y * 128 + tx * 4;

  float acc[8][4];
  #pragma unroll
  for (int r = 0; r < 8; r++)
    #pragma unroll
    for (int j = 0; j < 4; j++) acc[r][j] = 0.f;

  #pragma unroll 4
  for (int k4 = 0; k4 < 32; k4++) {
    const float* wr = W1 + (size_t)(k4 * 4) * ldW + n;
    float4 w0 = *(const float4*)(wr);
    float4 w1 = *(const float4*)(wr + ldW);
    float4 w2 = *(const float4*)(wr + 2 * (size_t)ldW);
    float4 w3 = *(const float4*)(wr + 3 * (size_t)ldW);
    #pragma unroll
    for (int r = 0; r < 8; r++) {
      float4 a = *(const float4*)&As[(ty + r * 8) * 128 + k4 * 4];
      acc[r][0] += a.x*w0.x + a.y*w1.x + a.z*w2.x + a.w*w3.x;
      acc[r][1] += a.x*w0.y + a.y*w1.y + a.z*w2.y + a.w*w3.y;
      acc[r][2] += a.x*w0.z + a.y*w1.z + a.z*w2.z + a.w*w3.z;
      acc[r][3] += a.x*w0.w + a.y*w1.w + a.z*w2.w + a.w*w3.w;
    }
  }
  if (HASB) {
    #pragma unroll 4
    for (int k4 = 0; k4 < 32; k4++) {
      const float* wr = W2 + (size_t)(k4 * 4) * ldW + n;
      float4 w0 = *(const float4*)(wr);
      float4 w1 = *(const float4*)(wr + ldW);
      float4 w2 = *(const float4*)(wr + 2 * (size_t)ldW);
      float4 w3 = *(const float4*)(wr + 3 * (size_t)ldW);
      #pragma unroll
      for (int r = 0; r < 8; r++) {
        float4 a = *(const float4*)&Bs[(ty + r * 8) * 128 + k4 * 4];
        acc[r][0] += a.x*w0.x + a.y*w1.x + a.z*w2.x + a.w*w3.x;
        acc[r][1] += a.x*w0.y + a.y*w1.y + a.z*w2.y + a.w*w3.y;
        acc[r][2] += a.x*w0.z + a.y*w1.z + a.z*w2.z + a.w*w3.z;
        acc[r][3] += a.x*w0.w + a.y*w1.w + a.z*w2.w + a.w*w3.w;
      }
    }
  }
  float4 bv = make_float4(0.f, 0.f, 0.f, 0.f);
  if (bias) bv = *(const float4*)&bias[n];
  #pragma unroll
  for (int r = 0; r < 8; r++) {
    int m = m0 + ty + r * 8;
    float4 o;
    o.x = acc[r][0] + bv.x; o.y = acc[r][1] + bv.y;
    o.z = acc[r][2] + bv.z; o.w = acc[r][3] + bv.w;
    if (RELU) {
      o.x = fmaxf(o.x, 0.f); o.y = fmaxf(o.y, 0.f);
      o.z = fmaxf(o.z, 0.f); o.w = fmaxf(o.w, 0.f);
    }
    if (HASRES) {
      float4 rr = *(const float4*)&Res[(size_t)m * ldOut + n];
      o.x += rr.x; o.y += rr.y; o.z += rr.z; o.w += rr.w;
    }
    *(float4*)&out[(size_t)m * ldOut + n] = o;
  }
}

// ---------------- fused message + mean-aggregation ----------------
// agg[j] = inv_deg(j) * sum_{i in in(j)} relu(A[i] + B[j])   (B already has bias)
__global__ __launch_bounds__(128) void agg_kernel(const float* __restrict__ Abuf,
                                                  const float* __restrict__ Bbuf,
                                                  const int* __restrict__ row_ptr,
                                                  const int* __restrict__ col,
                                                  float* __restrict__ agg) {
  int j = blockIdx.x;
  int c = threadIdx.x;
  float bj = Bbuf[(size_t)j * HID + c];
  int s = row_ptr[j], e = row_ptr[j + 1];
  float acc = 0.f;
  for (int p = s; p < e; p++) {
    int i = col[p];
    float v = Abuf[(size_t)i * HID + c] + bj;
    acc += fmaxf(v, 0.f);
  }
  float deg = (float)(e - s);
  float inv = 1.0f / fmaxf(deg, 1.0f);
  agg[(size_t)j * HID + c] = acc * inv;
}

__global__ __launch_bounds__(256) void copy_kernel(const float* __restrict__ src,
                                                   float* __restrict__ dst) {
  int t = blockIdx.x * 256 + threadIdx.x;
  ((float4*)dst)[t] = ((const float4*)src)[t];
}

extern "C" void kernel_launch(void* const* d_in, const int* in_sizes, int n_in,
                              void* d_out, int out_size, void* d_ws, size_t ws_size,
                              hipStream_t stream) {
  (void)in_sizes; (void)n_in; (void)out_size; (void)ws_size;
  const float* x       = (const float*)d_in[0];
  const float* pos     = (const float*)d_in[1];
  const float* enc_w0  = (const float*)d_in[3];
  const float* enc_b0  = (const float*)d_in[4];
  const float* enc_w1  = (const float*)d_in[5];
  const float* enc_b1  = (const float*)d_in[6];
  const float* msg_w   = (const float*)d_in[7];
  const float* msg_b   = (const float*)d_in[8];
  const float* upd_w   = (const float*)d_in[9];
  const float* upd_b   = (const float*)d_in[10];
  const float* proj_w0 = (const float*)d_in[11];
  const float* proj_b0 = (const float*)d_in[12];
  const float* proj_w1 = (const float*)d_in[13];
  const float* proj_b1 = (const float*)d_in[14];

  char* ws = (char*)d_ws;
  size_t off = 0;
  auto alloc = [&](size_t bytes) -> void* {
    void* p = ws + off;
    off += (bytes + 255) & ~(size_t)255;
    return p;
  };
  int*   nbr     = (int*)alloc((size_t)EE * 4);
  int*   cnt     = (int*)alloc((size_t)BN * 4);
  int*   fill    = (int*)alloc((size_t)BN * 4);
  int*   row_ptr = (int*)alloc((size_t)(BN + 1) * 4);
  int*   col     = (int*)alloc((size_t)EE * 4);
  float* h_a     = (float*)alloc((size_t)BN * HID * 4);
  float* h_b     = (float*)alloc((size_t)BN * HID * 4);
  float* bufA    = (float*)alloc((size_t)BN * HID * 4);
  float* bufB    = (float*)alloc((size_t)BN * HID * 4);
  float* bufAgg  = (float*)alloc((size_t)BN * HID * 4);
  float* out     = (float*)d_out;

  // cnt and fill are contiguous -> one memset
  hipMemsetAsync(cnt, 0, (size_t)BN * 4 * 2, stream);

  knn_kernel<<<BN, 64, 0, stream>>>(pos, nbr);
  count_kernel<<<EE / 256, 256, 0, stream>>>(nbr, cnt);
  scan_kernel<<<1, 256, 0, stream>>>(cnt, row_ptr);
  fill_kernel<<<EE / 256, 256, 0, stream>>>(nbr, row_ptr, fill, col);

  enc0_kernel<<<BN * 32 / 256, 256, 0, stream>>>(x, enc_w0, enc_b0, bufA);
  gemm_kernel<0,1,0><<<dim3(BN / 64, 1), 256, 0, stream>>>(
      bufA, enc_w1, nullptr, nullptr, enc_b1, nullptr, h_a, HID, HID);

  float* hc = h_a;
  float* hn = h_b;
  for (int i = 0; i < 3; i++) {
    const float* Wm = msg_w + (size_t)i * 256 * HID;
    gemm_kernel<0,0,0><<<dim3(BN / 64, 1), 256, 0, stream>>>(
        hc, Wm, nullptr, nullptr, nullptr, nullptr, bufA, HID, HID);
    gemm_kernel<0,0,0><<<dim3(BN / 64, 1), 256, 0, stream>>>(
        hc, Wm + 128 * HID, nullptr, nullptr, msg_b + (size_t)i * HID, nullptr,
        bufB, HID, HID);
    agg_kernel<<<BN, 128, 0, stream>>>(bufA, bufB, row_ptr, col, bufAgg);
    const float* Wu = upd_w + (size_t)i * 256 * HID;
    gemm_kernel<1,1,1><<<dim3(BN / 64, 1), 256, 0, stream>>>(
        hc, Wu, bufAgg, Wu + 128 * HID, upd_b + (size_t)i * HID, hc, hn, HID, HID);
    float* tmp = hc; hc = hn; hn = tmp;
  }

  gemm_kernel<0,1,0><<<dim3(BN / 64, 1), 256, 0, stream>>>(
      hc, proj_w0, nullptr, nullptr, proj_b0, nullptr, bufA, HID, HID);
  gemm_kernel<0,0,0><<<dim3(BN / 64, 2), 256, 0, stream>>>(
      bufA, proj_w1, nullptr, nullptr, proj_b1, nullptr, out, PROJ_D, PROJ_D);
  copy_kernel<<<BN * HID / 4 / 256, 256, 0, stream>>>(hc, out + (size_t)BN * PROJ_D);
}

// Round 2
// 560.298 us; speedup vs baseline: 1.3199x; 1.3199x over previous
//
#include <hip/hip_runtime.h>
#include <stdint.h>

#define NN 2048
#define BB 8
#define BN (BB*NN)
#define KK 16
#define EE (BN*KK)
#define HID 128
#define PROJ_D 256
#define QPB 16   // queries (waves) per knn block

typedef unsigned long long u64;

__device__ __forceinline__ u64 wave_min_u64(u64 v) {
  #pragma unroll
  for (int off = 32; off > 0; off >>= 1) {
    u64 o = __shfl_xor(v, off);
    v = o < v ? o : v;
  }
  return v;
}

// ---------------- kNN: 16 waves per block, one query per wave ----------------
__global__ __launch_bounds__(1024) void knn_kernel(const float* __restrict__ pos,
                                                   int* __restrict__ nbr) {
  __shared__ float4 Ps[NN];
  const int b  = blockIdx.x >> 7;          // / (NN/QPB) = /128
  const int qb = blockIdx.x & 127;
  const int wave = threadIdx.x >> 6;
  const int lane = threadIdx.x & 63;
  const int i = qb * QPB + wave;           // query index within batch
  const float* P = pos + (size_t)b * NN * 3;

  for (int t = threadIdx.x; t < NN; t += 1024)
    Ps[t] = make_float4(P[t*3], P[t*3+1], P[t*3+2], 0.f);
  __syncthreads();

  const float4 pi = Ps[i];
  const float xi = pi.x, yi = pi.y, zi = pi.z;

  u64 best[17];
  #pragma unroll
  for (int t = 0; t < 17; t++) best[t] = ~0ull;

  for (int j = lane; j < NN; j += 64) {
    float4 pj = Ps[j];
    float dx = fabsf(xi - pj.x);
    float dy = fabsf(yi - pj.y);
    float dz = fabsf(zi - pj.z);
    if (dx > 0.5f) dx = 1.0f - dx;
    if (dy > 0.5f) dy = 1.0f - dy;
    if (dz > 0.5f) dz = 1.0f - dz;
    // match numpy fp32 exactly: no FMA contraction, sum order ((x+y)+z)+eps
    float s = __fadd_rn(__fadd_rn(__fadd_rn(__fmul_rn(dx,dx), __fmul_rn(dy,dy)),
                                  __fmul_rn(dz,dz)), 1e-12f);
    float d = __fsqrt_rn(s);
    u64 key = ((u64)__float_as_uint(d) << 32) | (unsigned)j;
    if (key < best[16]) {
      best[16] = key;
      #pragma unroll
      for (int t = 16; t > 0; t--) {   // one bubble pass, static indices only
        u64 a = best[t-1], c = best[t];
        best[t-1] = a < c ? a : c;
        best[t]   = a < c ? c : a;
      }
    }
  }

  int* outp = nbr + ((size_t)b * NN + i) * KK;
  #pragma unroll 1
  for (int r = 0; r < KK + 1; r++) {
    u64 h = best[0];
    u64 m = wave_min_u64(h);
    if (r >= 1 && lane == 0) outp[r-1] = b * NN + (int)(m & 0xffffffffu);
    bool pop = (h == m);               // exactly one lane matches (keys unique)
    #pragma unroll
    for (int t = 0; t < 16; t++) best[t] = pop ? best[t+1] : best[t];
    best[16] = pop ? ~0ull : best[16];
  }
}

// ---------------- CSR build ----------------
__global__ __launch_bounds__(256) void count_kernel(const int* __restrict__ nbr,
                                                    int* __restrict__ cnt) {
  int e = blockIdx.x * 256 + threadIdx.x;
  atomicAdd(&cnt[nbr[e]], 1);
}

__global__ __launch_bounds__(256) void scan_kernel(const int* __restrict__ cnt,
                                                   int* __restrict__ row_ptr) {
  __shared__ int ps[256];
  int t = threadIdx.x;
  int base = t * 64;
  int s = 0;
  for (int i = 0; i < 64; i++) s += cnt[base + i];
  ps[t] = s;
  __syncthreads();
  for (int off = 1; off < 256; off <<= 1) {
    int v = 0;
    if (t >= off) v = ps[t - off];
    __syncthreads();
    ps[t] += v;
    __syncthreads();
  }
  int run = t ? ps[t - 1] : 0;
  for (int i = 0; i < 64; i++) { row_ptr[base + i] = run; run += cnt[base + i]; }
  if (t == 255) row_ptr[BN] = run;
}

__global__ __launch_bounds__(256) void fill_kernel(const int* __restrict__ nbr,
                                                   const int* __restrict__ row_ptr,
                                                   int* __restrict__ fill,
                                                   int* __restrict__ col) {
  int e = blockIdx.x * 256 + threadIdx.x;
  int d = nbr[e];
  int srcn = e >> 4;                  // / KK
  int p = row_ptr[d] + atomicAdd(&fill[d], 1);
  col[p] = srcn;
}

// ---------------- encoder layer 0: (BN,5)@(5,128)+relu ----------------
__global__ __launch_bounds__(256) void enc0_kernel(const float* __restrict__ x,
                                                   const float* __restrict__ w0,
                                                   const float* __restrict__ b0,
                                                   float* __restrict__ h) {
  int t = blockIdx.x * 256 + threadIdx.x;
  int m = t >> 5;
  int c = (t & 31) * 4;
  float xv[5];
  #pragma unroll
  for (int d = 0; d < 5; d++) xv[d] = x[m * 5 + d];
  float4 acc = *(const float4*)&b0[c];
  #pragma unroll
  for (int d = 0; d < 5; d++) {
    float4 w = *(const float4*)&w0[d * HID + c];
    acc.x += xv[d] * w.x; acc.y += xv[d] * w.y;
    acc.z += xv[d] * w.z; acc.w += xv[d] * w.w;
  }
  acc.x = fmaxf(acc.x, 0.f); acc.y = fmaxf(acc.y, 0.f);
  acc.z = fmaxf(acc.z, 0.f); acc.w = fmaxf(acc.w, 0.f);
  *(float4*)&h[(size_t)m * HID + c] = acc;
}

// ---------------- generic skinny GEMM: out = act(A@W1 [+ B@W2] + bias) [+ Res]
// block: 64 rows x 128 cols, 256 threads, each thread 8x4 outputs
template<int HASB, int RELU, int HASRES>
__global__ __launch_bounds__(256) void gemm_kernel(
    const float* __restrict__ A, const float* __restrict__ W1,
    const float* __restrict__ Bi, const float* __restrict__ W2,
    const float* __restrict__ bias, const float* __restrict__ Res,
    float* __restrict__ out, int ldW, int ldOut) {
  __shared__ float As[64 * 128];
  __shared__ float Bs[HASB ? 64 * 128 : 4];
  const int m0 = blockIdx.x * 64;
  {
    const float4* Ap = (const float4*)(A + (size_t)m0 * 128);
    const float4* Bp = HASB ? (const float4*)(Bi + (size_t)m0 * 128) : nullptr;
    for (int t = threadIdx.x; t < 64 * 32; t += 256) {
      ((float4*)As)[t] = Ap[t];
      if (HASB) ((float4*)Bs)[t] = Bp[t];
    }
  }
  __syncthreads();
  const int tx = threadIdx.x & 31, ty = threadIdx.x >> 5;
  const int n = blockIdx.y * 128 + tx * 4;

  float acc[8][4];
  #pragma unroll
  for (int r = 0; r < 8; r++)
    #pragma unroll
    for (int j = 0; j < 4; j++) acc[r][j] = 0.f;

  #pragma unroll 4
  for (int k4 = 0; k4 < 32; k4++) {
    const float* wr = W1 + (size_t)(k4 * 4) * ldW + n;
    float4 w0 = *(const float4*)(wr);
    float4 w1 = *(const float4*)(wr + ldW);
    float4 w2 = *(const float4*)(wr + 2 * (size_t)ldW);
    float4 w3 = *(const float4*)(wr + 3 * (size_t)ldW);
    #pragma unroll
    for (int r = 0; r < 8; r++) {
      float4 a = *(const float4*)&As[(ty + r * 8) * 128 + k4 * 4];
      acc[r][0] += a.x*w0.x + a.y*w1.x + a.z*w2.x + a.w*w3.x;
      acc[r][1] += a.x*w0.y + a.y*w1.y + a.z*w2.y + a.w*w3.y;
      acc[r][2] += a.x*w0.z + a.y*w1.z + a.z*w2.z + a.w*w3.z;
      acc[r][3] += a.x*w0.w + a.y*w1.w + a.z*w2.w + a.w*w3.w;
    }
  }
  if (HASB) {
    #pragma unroll 4
    for (int k4 = 0; k4 < 32; k4++) {
      const float* wr = W2 + (size_t)(k4 * 4) * ldW + n;
      float4 w0 = *(const float4*)(wr);
      float4 w1 = *(const float4*)(wr + ldW);
      float4 w2 = *(const float4*)(wr + 2 * (size_t)ldW);
      float4 w3 = *(const float4*)(wr + 3 * (size_t)ldW);
      #pragma unroll
      for (int r = 0; r < 8; r++) {
        float4 a = *(const float4*)&Bs[(ty + r * 8) * 128 + k4 * 4];
        acc[r][0] += a.x*w0.x + a.y*w1.x + a.z*w2.x + a.w*w3.x;
        acc[r][1] += a.x*w0.y + a.y*w1.y + a.z*w2.y + a.w*w3.y;
        acc[r][2] += a.x*w0.z + a.y*w1.z + a.z*w2.z + a.w*w3.z;
        acc[r][3] += a.x*w0.w + a.y*w1.w + a.z*w2.w + a.w*w3.w;
      }
    }
  }
  float4 bv = make_float4(0.f, 0.f, 0.f, 0.f);
  if (bias) bv = *(const float4*)&bias[n];
  #pragma unroll
  for (int r = 0; r < 8; r++) {
    int m = m0 + ty + r * 8;
    float4 o;
    o.x = acc[r][0] + bv.x; o.y = acc[r][1] + bv.y;
    o.z = acc[r][2] + bv.z; o.w = acc[r][3] + bv.w;
    if (RELU) {
      o.x = fmaxf(o.x, 0.f); o.y = fmaxf(o.y, 0.f);
      o.z = fmaxf(o.z, 0.f); o.w = fmaxf(o.w, 0.f);
    }
    if (HASRES) {
      float4 rr = *(const float4*)&Res[(size_t)m * ldOut + n];
      o.x += rr.x; o.y += rr.y; o.z += rr.z; o.w += rr.w;
    }
    *(float4*)&out[(size_t)m * ldOut + n] = o;
  }
}

// ---------------- fused message + mean-aggregation ----------------
// agg[j] = inv_deg(j) * sum_{i in in(j)} relu(A[i] + B[j])   (B already has bias)
__global__ __launch_bounds__(128) void agg_kernel(const float* __restrict__ Abuf,
                                                  const float* __restrict__ Bbuf,
                                                  const int* __restrict__ row_ptr,
                                                  const int* __restrict__ col,
                                                  float* __restrict__ agg) {
  int j = blockIdx.x;
  int c = threadIdx.x;
  float bj = Bbuf[(size_t)j * HID + c];
  int s = row_ptr[j], e = row_ptr[j + 1];
  float acc = 0.f;
  int p = s;
  // unroll-by-4: issue 4 independent index loads, then 4 row loads (MLP)
  for (; p + 4 <= e; p += 4) {
    int i0 = col[p], i1 = col[p+1], i2 = col[p+2], i3 = col[p+3];
    float v0 = Abuf[(size_t)i0 * HID + c];
    float v1 = Abuf[(size_t)i1 * HID + c];
    float v2 = Abuf[(size_t)i2 * HID + c];
    float v3 = Abuf[(size_t)i3 * HID + c];
    acc += fmaxf(v0 + bj, 0.f) + fmaxf(v1 + bj, 0.f)
         + fmaxf(v2 + bj, 0.f) + fmaxf(v3 + bj, 0.f);
  }
  for (; p < e; p++) {
    int i = col[p];
    acc += fmaxf(Abuf[(size_t)i * HID + c] + bj, 0.f);
  }
  float deg = (float)(e - s);
  float inv = 1.0f / fmaxf(deg, 1.0f);
  agg[(size_t)j * HID + c] = acc * inv;
}

__global__ __launch_bounds__(256) void copy_kernel(const float* __restrict__ src,
                                                   float* __restrict__ dst) {
  int t = blockIdx.x * 256 + threadIdx.x;
  ((float4*)dst)[t] = ((const float4*)src)[t];
}

extern "C" void kernel_launch(void* const* d_in, const int* in_sizes, int n_in,
                              void* d_out, int out_size, void* d_ws, size_t ws_size,
                              hipStream_t stream) {
  (void)in_sizes; (void)n_in; (void)out_size; (void)ws_size;
  const float* x       = (const float*)d_in[0];
  const float* pos     = (const float*)d_in[1];
  const float* enc_w0  = (const float*)d_in[3];
  const float* enc_b0  = (const float*)d_in[4];
  const float* enc_w1  = (const float*)d_in[5];
  const float* enc_b1  = (const float*)d_in[6];
  const float* msg_w   = (const float*)d_in[7];
  const float* msg_b   = (const float*)d_in[8];
  const float* upd_w   = (const float*)d_in[9];
  const float* upd_b   = (const float*)d_in[10];
  const float* proj_w0 = (const float*)d_in[11];
  const float* proj_b0 = (const float*)d_in[12];
  const float* proj_w1 = (const float*)d_in[13];
  const float* proj_b1 = (const float*)d_in[14];

  char* ws = (char*)d_ws;
  size_t off = 0;
  auto alloc = [&](size_t bytes) -> void* {
    void* p = ws + off;
    off += (bytes + 255) & ~(size_t)255;
    return p;
  };
  int*   nbr     = (int*)alloc((size_t)EE * 4);
  int*   cnt     = (int*)alloc((size_t)BN * 4);
  int*   fill    = (int*)alloc((size_t)BN * 4);
  int*   row_ptr = (int*)alloc((size_t)(BN + 1) * 4);
  int*   col     = (int*)alloc((size_t)EE * 4);
  float* h_a     = (float*)alloc((size_t)BN * HID * 4);
  float* h_b     = (float*)alloc((size_t)BN * HID * 4);
  float* bufA    = (float*)alloc((size_t)BN * HID * 4);
  float* bufB    = (float*)alloc((size_t)BN * HID * 4);
  float* bufAgg  = (float*)alloc((size_t)BN * HID * 4);
  float* out     = (float*)d_out;

  // cnt and fill are contiguous -> one memset
  hipMemsetAsync(cnt, 0, (size_t)BN * 4 * 2, stream);

  knn_kernel<<<BN / QPB, 1024, 0, stream>>>(pos, nbr);
  count_kernel<<<EE / 256, 256, 0, stream>>>(nbr, cnt);
  scan_kernel<<<1, 256, 0, stream>>>(cnt, row_ptr);
  fill_kernel<<<EE / 256, 256, 0, stream>>>(nbr, row_ptr, fill, col);

  enc0_kernel<<<BN * 32 / 256, 256, 0, stream>>>(x, enc_w0, enc_b0, bufA);
  gemm_kernel<0,1,0><<<dim3(BN / 64, 1), 256, 0, stream>>>(
      bufA, enc_w1, nullptr, nullptr, enc_b1, nullptr, h_a, HID, HID);

  float* hc = h_a;
  float* hn = h_b;
  for (int i = 0; i < 3; i++) {
    const float* Wm = msg_w + (size_t)i * 256 * HID;
    gemm_kernel<0,0,0><<<dim3(BN / 64, 1), 256, 0, stream>>>(
        hc, Wm, nullptr, nullptr, nullptr, nullptr, bufA, HID, HID);
    gemm_kernel<0,0,0><<<dim3(BN / 64, 1), 256, 0, stream>>>(
        hc, Wm + 128 * HID, nullptr, nullptr, msg_b + (size_t)i * HID, nullptr,
        bufB, HID, HID);
    agg_kernel<<<BN, 128, 0, stream>>>(bufA, bufB, row_ptr, col, bufAgg);
    const float* Wu = upd_w + (size_t)i * 256 * HID;
    gemm_kernel<1,1,1><<<dim3(BN / 64, 1), 256, 0, stream>>>(
        hc, Wu, bufAgg, Wu + 128 * HID, upd_b + (size_t)i * HID, hc, hn, HID, HID);
    float* tmp = hc; hc = hn; hn = tmp;
  }

  gemm_kernel<0,1,0><<<dim3(BN / 64, 1), 256, 0, stream>>>(
      hc, proj_w0, nullptr, nullptr, proj_b0, nullptr, bufA, HID, HID);
  gemm_kernel<0,0,0><<<dim3(BN / 64, 2), 256, 0, stream>>>(
      bufA, proj_w1, nullptr, nullptr, proj_b1, nullptr, out, PROJ_D, PROJ_D);
  copy_kernel<<<BN * HID / 4 / 256, 256, 0, stream>>>(hc, out + (size_t)BN * PROJ_D);
}

// Round 3
// 515.792 us; speedup vs baseline: 1.4338x; 1.0863x over previous
//
#include <hip/hip_runtime.h>
#include <stdint.h>
#include <math.h>

#define NN 2048
#define BB 8
#define BN (BB*NN)
#define KK 16
#define EE (BN*KK)
#define HID 128
#define PROJ_D 256
#define QPB 16   // queries (waves) per knn block

typedef unsigned long long u64;

__device__ __forceinline__ double wave_min_f64(double v) {
  #pragma unroll
  for (int off = 32; off > 0; off >>= 1) {
    double o = __shfl_xor(v, off);
    v = fmin(v, o);
  }
  return v;
}

// ---------------- kNN: 16 waves per block, one query per wave ----------------
// key = dist_bits * 2048 + j  (exact integer in double, < 2^41)
// -> compare-exchange is v_min_f64/v_max_f64 (2 insts vs 5 for u64)
__global__ __launch_bounds__(1024) void knn_kernel(const float* __restrict__ pos,
                                                   int* __restrict__ nbr) {
  __shared__ float4 Ps[NN];
  const int b  = blockIdx.x >> 7;          // / (NN/QPB) = /128
  const int qb = blockIdx.x & 127;
  const int wave = threadIdx.x >> 6;
  const int lane = threadIdx.x & 63;
  const int i = qb * QPB + wave;           // query index within batch
  const float* P = pos + (size_t)b * NN * 3;

  for (int t = threadIdx.x; t < NN; t += 1024)
    Ps[t] = make_float4(P[t*3], P[t*3+1], P[t*3+2], 0.f);
  __syncthreads();

  const float4 pi = Ps[i];
  const float xi = pi.x, yi = pi.y, zi = pi.z;

  const double INF = __builtin_inf();
  double best[17];
  #pragma unroll
  for (int t = 0; t < 17; t++) best[t] = INF;

  for (int j = lane; j < NN; j += 64) {
    float4 pj = Ps[j];
    float dx = fabsf(xi - pj.x);
    float dy = fabsf(yi - pj.y);
    float dz = fabsf(zi - pj.z);
    if (dx > 0.5f) dx = 1.0f - dx;
    if (dy > 0.5f) dy = 1.0f - dy;
    if (dz > 0.5f) dz = 1.0f - dz;
    // match numpy fp32 exactly: no FMA contraction, sum order ((x+y)+z)+eps
    float s = __fadd_rn(__fadd_rn(__fadd_rn(__fmul_rn(dx,dx), __fmul_rn(dy,dy)),
                                  __fmul_rn(dz,dz)), 1e-12f);
    float d = __fsqrt_rn(s);
    unsigned bits = __float_as_uint(d);
    double key = __fma_rn((double)bits, 2048.0, (double)j);  // exact
    if (key < best[16]) {
      best[16] = key;
      #pragma unroll
      for (int t = 16; t > 0; t--) {   // one bubble pass: min/max CEs
        double a = best[t-1], c = best[t];
        best[t-1] = fmin(a, c);
        best[t]   = fmax(a, c);
      }
    }
  }

  int* outp = nbr + ((size_t)b * NN + i) * KK;
  #pragma unroll 1
  for (int r = 0; r < KK + 1; r++) {
    double h = best[0];
    double m = wave_min_f64(h);
    if (r >= 1 && lane == 0)
      outp[r-1] = b * NN + (int)((u64)m & 2047u);
    bool pop = (h == m);               // exactly one lane matches (keys unique)
    #pragma unroll
    for (int t = 0; t < 16; t++) best[t] = pop ? best[t+1] : best[t];
    best[16] = pop ? INF : best[16];
  }
}

// ---------------- CSR build ----------------
__global__ __launch_bounds__(256) void count_kernel(const int* __restrict__ nbr,
                                                    int* __restrict__ cnt) {
  int e = blockIdx.x * 256 + threadIdx.x;
  atomicAdd(&cnt[nbr[e]], 1);
}

__global__ __launch_bounds__(256) void scan_kernel(const int* __restrict__ cnt,
                                                   int* __restrict__ row_ptr) {
  __shared__ int ps[256];
  int t = threadIdx.x;
  int base = t * 64;
  int s = 0;
  for (int i = 0; i < 64; i++) s += cnt[base + i];
  ps[t] = s;
  __syncthreads();
  for (int off = 1; off < 256; off <<= 1) {
    int v = 0;
    if (t >= off) v = ps[t - off];
    __syncthreads();
    ps[t] += v;
    __syncthreads();
  }
  int run = t ? ps[t - 1] : 0;
  for (int i = 0; i < 64; i++) { row_ptr[base + i] = run; run += cnt[base + i]; }
  if (t == 255) row_ptr[BN] = run;
}

__global__ __launch_bounds__(256) void fill_kernel(const int* __restrict__ nbr,
                                                   const int* __restrict__ row_ptr,
                                                   int* __restrict__ fill,
                                                   int* __restrict__ col) {
  int e = blockIdx.x * 256 + threadIdx.x;
  int d = nbr[e];
  int srcn = e >> 4;                  // / KK
  int p = row_ptr[d] + atomicAdd(&fill[d], 1);
  col[p] = srcn;
}

// ---------------- encoder layer 0: (BN,5)@(5,128)+relu ----------------
__global__ __launch_bounds__(256) void enc0_kernel(const float* __restrict__ x,
                                                   const float* __restrict__ w0,
                                                   const float* __restrict__ b0,
                                                   float* __restrict__ h) {
  int t = blockIdx.x * 256 + threadIdx.x;
  int m = t >> 5;
  int c = (t & 31) * 4;
  float xv[5];
  #pragma unroll
  for (int d = 0; d < 5; d++) xv[d] = x[m * 5 + d];
  float4 acc = *(const float4*)&b0[c];
  #pragma unroll
  for (int d = 0; d < 5; d++) {
    float4 w = *(const float4*)&w0[d * HID + c];
    acc.x += xv[d] * w.x; acc.y += xv[d] * w.y;
    acc.z += xv[d] * w.z; acc.w += xv[d] * w.w;
  }
  acc.x = fmaxf(acc.x, 0.f); acc.y = fmaxf(acc.y, 0.f);
  acc.z = fmaxf(acc.z, 0.f); acc.w = fmaxf(acc.w, 0.f);
  *(float4*)&h[(size_t)m * HID + c] = acc;
}

// ---------------- generic skinny GEMM: out = act(A@W1 [+ B@W2] + bias) [+ Res]
// 32-row x 128-col tiles, 256 threads, each thread 4x4 outputs. grid.x = BN/32.
template<int HASB, int RELU, int HASRES>
__global__ __launch_bounds__(256) void gemm32(
    const float* __restrict__ A, const float* __restrict__ W1,
    const float* __restrict__ Bi, const float* __restrict__ W2,
    const float* __restrict__ bias, const float* __restrict__ Res,
    float* __restrict__ out, int ldW, int ldOut) {
  __shared__ float As[32 * 128];
  __shared__ float Bs[HASB ? 32 * 128 : 4];
  const int m0 = blockIdx.x * 32;
  {
    const float4* Ap = (const float4*)(A + (size_t)m0 * 128);
    const float4* Bp = HASB ? (const float4*)(Bi + (size_t)m0 * 128) : nullptr;
    #pragma unroll
    for (int t = 0; t < 4; t++) {
      int idx = threadIdx.x + 256 * t;
      ((float4*)As)[idx] = Ap[idx];
      if (HASB) ((float4*)Bs)[idx] = Bp[idx];
    }
  }
  __syncthreads();
  const int tx = threadIdx.x & 31, ty = threadIdx.x >> 5;
  const int n = blockIdx.y * 128 + tx * 4;

  float acc[4][4];
  #pragma unroll
  for (int r = 0; r < 4; r++)
    #pragma unroll
    for (int j = 0; j < 4; j++) acc[r][j] = 0.f;

  #pragma unroll 4
  for (int k4 = 0; k4 < 32; k4++) {
    const float* wr = W1 + (size_t)(k4 * 4) * ldW + n;
    float4 w0 = *(const float4*)(wr);
    float4 w1 = *(const float4*)(wr + ldW);
    float4 w2 = *(const float4*)(wr + 2 * (size_t)ldW);
    float4 w3 = *(const float4*)(wr + 3 * (size_t)ldW);
    #pragma unroll
    for (int r = 0; r < 4; r++) {
      float4 a = *(const float4*)&As[(ty + r * 8) * 128 + k4 * 4];
      acc[r][0] += a.x*w0.x + a.y*w1.x + a.z*w2.x + a.w*w3.x;
      acc[r][1] += a.x*w0.y + a.y*w1.y + a.z*w2.y + a.w*w3.y;
      acc[r][2] += a.x*w0.z + a.y*w1.z + a.z*w2.z + a.w*w3.z;
      acc[r][3] += a.x*w0.w + a.y*w1.w + a.z*w2.w + a.w*w3.w;
    }
  }
  if (HASB) {
    #pragma unroll 4
    for (int k4 = 0; k4 < 32; k4++) {
      const float* wr = W2 + (size_t)(k4 * 4) * ldW + n;
      float4 w0 = *(const float4*)(wr);
      float4 w1 = *(const float4*)(wr + ldW);
      float4 w2 = *(const float4*)(wr + 2 * (size_t)ldW);
      float4 w3 = *(const float4*)(wr + 3 * (size_t)ldW);
      #pragma unroll
      for (int r = 0; r < 4; r++) {
        float4 a = *(const float4*)&Bs[(ty + r * 8) * 128 + k4 * 4];
        acc[r][0] += a.x*w0.x + a.y*w1.x + a.z*w2.x + a.w*w3.x;
        acc[r][1] += a.x*w0.y + a.y*w1.y + a.z*w2.y + a.w*w3.y;
        acc[r][2] += a.x*w0.z + a.y*w1.z + a.z*w2.z + a.w*w3.z;
        acc[r][3] += a.x*w0.w + a.y*w1.w + a.z*w2.w + a.w*w3.w;
      }
    }
  }
  float4 bv = make_float4(0.f, 0.f, 0.f, 0.f);
  if (bias) bv = *(const float4*)&bias[n];
  #pragma unroll
  for (int r = 0; r < 4; r++) {
    int m = m0 + ty + r * 8;
    float4 o;
    o.x = acc[r][0] + bv.x; o.y = acc[r][1] + bv.y;
    o.z = acc[r][2] + bv.z; o.w = acc[r][3] + bv.w;
    if (RELU) {
      o.x = fmaxf(o.x, 0.f); o.y = fmaxf(o.y, 0.f);
      o.z = fmaxf(o.z, 0.f); o.w = fmaxf(o.w, 0.f);
    }
    if (HASRES) {
      float4 rr = *(const float4*)&Res[(size_t)m * ldOut + n];
      o.x += rr.x; o.y += rr.y; o.z += rr.z; o.w += rr.w;
    }
    *(float4*)&out[(size_t)m * ldOut + n] = o;
  }
}

// ---------------- fused msg pair: outA = A@Wtop ; outB = A@Wbot + bias ------
// shares the A-stage between both products; 32-row tiles, grid = BN/32
__global__ __launch_bounds__(256) void msg2_kernel(
    const float* __restrict__ A, const float* __restrict__ Wtop,
    const float* __restrict__ Wbot, const float* __restrict__ bias,
    float* __restrict__ outA, float* __restrict__ outB) {
  __shared__ float As[32 * 128];
  const int m0 = blockIdx.x * 32;
  {
    const float4* Ap = (const float4*)(A + (size_t)m0 * 128);
    #pragma unroll
    for (int t = 0; t < 4; t++) {
      int idx = threadIdx.x + 256 * t;
      ((float4*)As)[idx] = Ap[idx];
    }
  }
  __syncthreads();
  const int tx = threadIdx.x & 31, ty = threadIdx.x >> 5;
  const int n = tx * 4;

  #pragma unroll 1
  for (int phase = 0; phase < 2; phase++) {
    const float* W = phase ? Wbot : Wtop;
    float acc[4][4];
    #pragma unroll
    for (int r = 0; r < 4; r++)
      #pragma unroll
      for (int j = 0; j < 4; j++) acc[r][j] = 0.f;
    #pragma unroll 4
    for (int k4 = 0; k4 < 32; k4++) {
      const float* wr = W + (size_t)(k4 * 4) * HID + n;
      float4 w0 = *(const float4*)(wr);
      float4 w1 = *(const float4*)(wr + HID);
      float4 w2 = *(const float4*)(wr + 2 * HID);
      float4 w3 = *(const float4*)(wr + 3 * HID);
      #pragma unroll
      for (int r = 0; r < 4; r++) {
        float4 a = *(const float4*)&As[(ty + r * 8) * 128 + k4 * 4];
        acc[r][0] += a.x*w0.x + a.y*w1.x + a.z*w2.x + a.w*w3.x;
        acc[r][1] += a.x*w0.y + a.y*w1.y + a.z*w2.y + a.w*w3.y;
        acc[r][2] += a.x*w0.z + a.y*w1.z + a.z*w2.z + a.w*w3.z;
        acc[r][3] += a.x*w0.w + a.y*w1.w + a.z*w2.w + a.w*w3.w;
      }
    }
    float4 bv = make_float4(0.f, 0.f, 0.f, 0.f);
    if (phase) bv = *(const float4*)&bias[n];
    float* out = phase ? outB : outA;
    #pragma unroll
    for (int r = 0; r < 4; r++) {
      int m = m0 + ty + r * 8;
      float4 o;
      o.x = acc[r][0] + bv.x; o.y = acc[r][1] + bv.y;
      o.z = acc[r][2] + bv.z; o.w = acc[r][3] + bv.w;
      *(float4*)&out[(size_t)m * HID + n] = o;
    }
  }
}

// ---------------- fused message + mean-aggregation ----------------
// agg[j] = inv_deg(j) * sum_{i in in(j)} relu(A[i] + B[j])   (B already has bias)
__global__ __launch_bounds__(128) void agg_kernel(const float* __restrict__ Abuf,
                                                  const float* __restrict__ Bbuf,
                                                  const int* __restrict__ row_ptr,
                                                  const int* __restrict__ col,
                                                  float* __restrict__ agg) {
  int j = blockIdx.x;
  int c = threadIdx.x;
  float bj = Bbuf[(size_t)j * HID + c];
  int s = row_ptr[j], e = row_ptr[j + 1];
  float acc = 0.f;
  int p = s;
  for (; p + 4 <= e; p += 4) {
    int i0 = col[p], i1 = col[p+1], i2 = col[p+2], i3 = col[p+3];
    float v0 = Abuf[(size_t)i0 * HID + c];
    float v1 = Abuf[(size_t)i1 * HID + c];
    float v2 = Abuf[(size_t)i2 * HID + c];
    float v3 = Abuf[(size_t)i3 * HID + c];
    acc += fmaxf(v0 + bj, 0.f) + fmaxf(v1 + bj, 0.f)
         + fmaxf(v2 + bj, 0.f) + fmaxf(v3 + bj, 0.f);
  }
  for (; p < e; p++) {
    int i = col[p];
    acc += fmaxf(Abuf[(size_t)i * HID + c] + bj, 0.f);
  }
  float deg = (float)(e - s);
  float inv = 1.0f / fmaxf(deg, 1.0f);
  agg[(size_t)j * HID + c] = acc * inv;
}

extern "C" void kernel_launch(void* const* d_in, const int* in_sizes, int n_in,
                              void* d_out, int out_size, void* d_ws, size_t ws_size,
                              hipStream_t stream) {
  (void)in_sizes; (void)n_in; (void)out_size; (void)ws_size;
  const float* x       = (const float*)d_in[0];
  const float* pos     = (const float*)d_in[1];
  const float* enc_w0  = (const float*)d_in[3];
  const float* enc_b0  = (const float*)d_in[4];
  const float* enc_w1  = (const float*)d_in[5];
  const float* enc_b1  = (const float*)d_in[6];
  const float* msg_w   = (const float*)d_in[7];
  const float* msg_b   = (const float*)d_in[8];
  const float* upd_w   = (const float*)d_in[9];
  const float* upd_b   = (const float*)d_in[10];
  const float* proj_w0 = (const float*)d_in[11];
  const float* proj_b0 = (const float*)d_in[12];
  const float* proj_w1 = (const float*)d_in[13];
  const float* proj_b1 = (const float*)d_in[14];

  char* ws = (char*)d_ws;
  size_t off = 0;
  auto alloc = [&](size_t bytes) -> void* {
    void* p = ws + off;
    off += (bytes + 255) & ~(size_t)255;
    return p;
  };
  int*   nbr     = (int*)alloc((size_t)EE * 4);
  int*   cnt     = (int*)alloc((size_t)BN * 4);
  int*   fill    = (int*)alloc((size_t)BN * 4);
  int*   row_ptr = (int*)alloc((size_t)(BN + 1) * 4);
  int*   col     = (int*)alloc((size_t)EE * 4);
  float* h_a     = (float*)alloc((size_t)BN * HID * 4);
  float* h_b     = (float*)alloc((size_t)BN * HID * 4);
  float* bufA    = (float*)alloc((size_t)BN * HID * 4);
  float* bufB    = (float*)alloc((size_t)BN * HID * 4);
  float* bufAgg  = (float*)alloc((size_t)BN * HID * 4);
  float* out     = (float*)d_out;
  float* hOut    = out + (size_t)BN * PROJ_D;   // final h written here directly

  // cnt and fill are contiguous -> one memset
  hipMemsetAsync(cnt, 0, (size_t)BN * 4 * 2, stream);

  knn_kernel<<<BN / QPB, 1024, 0, stream>>>(pos, nbr);
  count_kernel<<<EE / 256, 256, 0, stream>>>(nbr, cnt);
  scan_kernel<<<1, 256, 0, stream>>>(cnt, row_ptr);
  fill_kernel<<<EE / 256, 256, 0, stream>>>(nbr, row_ptr, fill, col);

  enc0_kernel<<<BN * 32 / 256, 256, 0, stream>>>(x, enc_w0, enc_b0, bufA);
  gemm32<0,1,0><<<dim3(BN / 32, 1), 256, 0, stream>>>(
      bufA, enc_w1, nullptr, nullptr, enc_b1, nullptr, h_a, HID, HID);

  float* hc = h_a;
  float* hn = h_b;
  for (int i = 0; i < 3; i++) {
    const float* Wm = msg_w + (size_t)i * 256 * HID;
    msg2_kernel<<<BN / 32, 256, 0, stream>>>(
        hc, Wm, Wm + 128 * HID, msg_b + (size_t)i * HID, bufA, bufB);
    agg_kernel<<<BN, 128, 0, stream>>>(bufA, bufB, row_ptr, col, bufAgg);
    const float* Wu = upd_w + (size_t)i * 256 * HID;
    float* target = (i == 2) ? hOut : hn;
    gemm32<1,1,1><<<dim3(BN / 32, 1), 256, 0, stream>>>(
        hc, Wu, bufAgg, Wu + 128 * HID, upd_b + (size_t)i * HID, hc, target, HID, HID);
    hn = hc; hc = target;
  }

  gemm32<0,1,0><<<dim3(BN / 32, 1), 256, 0, stream>>>(
      hc, proj_w0, nullptr, nullptr, proj_b0, nullptr, bufA, HID, HID);
  gemm32<0,0,0><<<dim3(BN / 32, 2), 256, 0, stream>>>(
      bufA, proj_w1, nullptr, nullptr, proj_b1, nullptr, out, PROJ_D, PROJ_D);
}

// Round 4
// 464.350 us; speedup vs baseline: 1.5926x; 1.1108x over previous
//
#include <hip/hip_runtime.h>
#include <stdint.h>
#include <math.h>

#define NN 2048
#define BB 8
#define BN (BB*NN)
#define KK 16
#define EE (BN*KK)
#define HID 128
#define PROJ_D 256
#define QPB 16   // queries (waves) per knn block

typedef unsigned long long u64;

__device__ __forceinline__ u64 wave_min_u64(u64 v) {
  #pragma unroll
  for (int off = 32; off > 0; off >>= 1) {
    u64 o = __shfl_xor(v, off);
    v = o < v ? o : v;
  }
  return v;
}

// ---------------- kNN: 16 waves per block, one query per wave ----------------
// Histogram selection (exact): edge ORDER is irrelevant downstream (CSR sum),
// only the exact top-17 SET with reference tie-break (dist_bits, then index).
// key = (dist_bits << 11) | j  -- unique, 43 bits, matches top_k semantics.
__global__ __launch_bounds__(1024) void knn_kernel(const float* __restrict__ pos,
                                                   int* __restrict__ nbr) {
  __shared__ float4 Ps[NN];            // 32 KB
  __shared__ unsigned Hist[QPB * 256]; // 16 KB, private 256 bins per wave
  const int b  = blockIdx.x >> 7;          // / (NN/QPB) = /128
  const int qb = blockIdx.x & 127;
  const int wave = threadIdx.x >> 6;
  const int lane = threadIdx.x & 63;
  const int i = qb * QPB + wave;           // query index within batch
  const float* P = pos + (size_t)b * NN * 3;

  for (int t = threadIdx.x; t < NN; t += 1024)
    Ps[t] = make_float4(P[t*3], P[t*3+1], P[t*3+2], 0.f);

  unsigned* H = &Hist[wave * 256];
  *(uint4*)&H[lane * 4] = make_uint4(0u, 0u, 0u, 0u);
  __syncthreads();   // Ps staged + hist zeroed (all waves uniform path)

  const float4 pi = Ps[i];
  const float xi = pi.x, yi = pi.y, zi = pi.z;

  // ---- pass 1: distances (exact reference arithmetic) + histogram ----
  float d[32];
  #pragma unroll
  for (int t = 0; t < 32; t++) {
    int j = t * 64 + lane;
    float4 pj = Ps[j];
    float dx = fabsf(xi - pj.x);
    float dy = fabsf(yi - pj.y);
    float dz = fabsf(zi - pj.z);
    if (dx > 0.5f) dx = 1.0f - dx;
    if (dy > 0.5f) dy = 1.0f - dy;
    if (dz > 0.5f) dz = 1.0f - dz;
    // match numpy fp32 exactly: no FMA contraction, sum order ((x+y)+z)+eps
    float s = __fadd_rn(__fadd_rn(__fadd_rn(__fmul_rn(dx,dx), __fmul_rn(dy,dy)),
                                  __fmul_rn(dz,dz)), 1e-12f);
    d[t] = __fsqrt_rn(s);
    int bin = (int)(d[t] * 256.0f);      // monotone in d; d < 0.867 -> bin < 222
    atomicAdd(&H[bin], 1u);
  }
  __syncthreads();   // all waves did exactly 32 iters -> uniform barrier

  // ---- find bin containing rank 17 (cumulative crossing) ----
  uint4 cv = *(const uint4*)&H[lane * 4];
  unsigned s4 = cv.x + cv.y + cv.z + cv.w;
  unsigned incl = s4;
  #pragma unroll
  for (int off = 1; off < 64; off <<= 1) {
    unsigned v = __shfl_up(incl, off);
    if (lane >= off) incl += v;
  }
  unsigned base = incl - s4;
  bool has = (incl >= 17u) && (base < 17u);   // exactly one lane
  u64 hmask = __ballot(has);
  int srcl = __ffsll((unsigned long long)hmask) - 1;
  int bstar = 0; unsigned C = 0;
  if (has) {
    if (base + cv.x >= 17u)                    { bstar = lane*4 + 0; C = base; }
    else if (base + cv.x + cv.y >= 17u)        { bstar = lane*4 + 1; C = base + cv.x; }
    else if (base + cv.x + cv.y + cv.z >= 17u) { bstar = lane*4 + 2; C = base + cv.x + cv.y; }
    else                                       { bstar = lane*4 + 3; C = base + cv.x + cv.y + cv.z; }
  }
  bstar = __shfl(bstar, srcl);
  C     = __shfl(C, srcl);
  const int m = 17 - (int)C;                   // 1..17 members needed from bin bstar

  // ---- per-lane sorted list (6 slots) of this lane's members of bin bstar ----
  // expected members/lane ~0.03; >6 is astronomically improbable
  u64 lst[6];
  #pragma unroll
  for (int t = 0; t < 6; t++) lst[t] = ~0ull;
  #pragma unroll
  for (int t = 0; t < 32; t++) {
    int bin = (int)(d[t] * 256.0f);
    u64 key = ((u64)__float_as_uint(d[t]) << 11) | (unsigned)(t * 64 + lane);
    u64 cand = (bin == bstar) ? key : ~0ull;
    if (cand < lst[5]) {
      lst[5] = cand;
      #pragma unroll
      for (int u = 5; u > 0; u--) {
        u64 a = lst[u-1], c2 = lst[u];
        lst[u-1] = a < c2 ? a : c2;
        lst[u]   = a < c2 ? c2 : a;
      }
    }
  }

  // ---- extract m smallest keys within bin bstar; kstar = 17th overall ----
  u64 kstar = 0;
  #pragma unroll 1
  for (int r = 0; r < m; r++) {
    u64 h0 = lst[0];
    u64 gm = wave_min_u64(h0);
    kstar = gm;
    bool win = (h0 == gm);
    #pragma unroll
    for (int u = 0; u < 5; u++) lst[u] = win ? lst[u+1] : lst[u];
    lst[5] = win ? ~0ull : lst[5];
  }

  // ---- emission: all keys <= kstar, excluding self; ballot compaction ----
  int* outp = nbr + ((size_t)b * NN + i) * KK;
  int total = 0;
  #pragma unroll
  for (int t = 0; t < 32; t++) {
    int j = t * 64 + lane;
    u64 key = ((u64)__float_as_uint(d[t]) << 11) | (unsigned)j;
    bool pred = (key <= kstar) && (j != i);
    u64 msk = __ballot(pred);
    if (pred) {
      int ofs = total + __popcll(msk & ((1ull << lane) - 1ull));
      outp[ofs] = b * NN + j;
    }
    total += __popcll(msk);
  }
}

// ---------------- CSR build ----------------
__global__ __launch_bounds__(256) void count_kernel(const int* __restrict__ nbr,
                                                    int* __restrict__ cnt) {
  int e = blockIdx.x * 256 + threadIdx.x;
  atomicAdd(&cnt[nbr[e]], 1);
}

__global__ __launch_bounds__(256) void scan_kernel(const int* __restrict__ cnt,
                                                   int* __restrict__ row_ptr) {
  __shared__ int ps[256];
  int t = threadIdx.x;
  int base = t * 64;
  int s = 0;
  for (int i = 0; i < 64; i++) s += cnt[base + i];
  ps[t] = s;
  __syncthreads();
  for (int off = 1; off < 256; off <<= 1) {
    int v = 0;
    if (t >= off) v = ps[t - off];
    __syncthreads();
    ps[t] += v;
    __syncthreads();
  }
  int run = t ? ps[t - 1] : 0;
  for (int i = 0; i < 64; i++) { row_ptr[base + i] = run; run += cnt[base + i]; }
  if (t == 255) row_ptr[BN] = run;
}

__global__ __launch_bounds__(256) void fill_kernel(const int* __restrict__ nbr,
                                                   const int* __restrict__ row_ptr,
                                                   int* __restrict__ fill,
                                                   int* __restrict__ col) {
  int e = blockIdx.x * 256 + threadIdx.x;
  int d = nbr[e];
  int srcn = e >> 4;                  // / KK
  int p = row_ptr[d] + atomicAdd(&fill[d], 1);
  col[p] = srcn;
}

// ---------------- encoder layer 0: (BN,5)@(5,128)+relu ----------------
__global__ __launch_bounds__(256) void enc0_kernel(const float* __restrict__ x,
                                                   const float* __restrict__ w0,
                                                   const float* __restrict__ b0,
                                                   float* __restrict__ h) {
  int t = blockIdx.x * 256 + threadIdx.x;
  int m = t >> 5;
  int c = (t & 31) * 4;
  float xv[5];
  #pragma unroll
  for (int d = 0; d < 5; d++) xv[d] = x[m * 5 + d];
  float4 acc = *(const float4*)&b0[c];
  #pragma unroll
  for (int d = 0; d < 5; d++) {
    float4 w = *(const float4*)&w0[d * HID + c];
    acc.x += xv[d] * w.x; acc.y += xv[d] * w.y;
    acc.z += xv[d] * w.z; acc.w += xv[d] * w.w;
  }
  acc.x = fmaxf(acc.x, 0.f); acc.y = fmaxf(acc.y, 0.f);
  acc.z = fmaxf(acc.z, 0.f); acc.w = fmaxf(acc.w, 0.f);
  *(float4*)&h[(size_t)m * HID + c] = acc;
}

// ---------------- generic skinny GEMM: out = act(A@W1 [+ B@W2] + bias) [+ Res]
// 32-row x 128-col tiles, 256 threads, each thread 4x4 outputs. grid.x = BN/32.
template<int HASB, int RELU, int HASRES>
__global__ __launch_bounds__(256) void gemm32(
    const float* __restrict__ A, const float* __restrict__ W1,
    const float* __restrict__ Bi, const float* __restrict__ W2,
    const float* __restrict__ bias, const float* __restrict__ Res,
    float* __restrict__ out, int ldW, int ldOut) {
  __shared__ float As[32 * 128];
  __shared__ float Bs[HASB ? 32 * 128 : 4];
  const int m0 = blockIdx.x * 32;
  {
    const float4* Ap = (const float4*)(A + (size_t)m0 * 128);
    const float4* Bp = HASB ? (const float4*)(Bi + (size_t)m0 * 128) : nullptr;
    #pragma unroll
    for (int t = 0; t < 4; t++) {
      int idx = threadIdx.x + 256 * t;
      ((float4*)As)[idx] = Ap[idx];
      if (HASB) ((float4*)Bs)[idx] = Bp[idx];
    }
  }
  __syncthreads();
  const int tx = threadIdx.x & 31, ty = threadIdx.x >> 5;
  const int n = blockIdx.y * 128 + tx * 4;

  float acc[4][4];
  #pragma unroll
  for (int r = 0; r < 4; r++)
    #pragma unroll
    for (int j = 0; j < 4; j++) acc[r][j] = 0.f;

  #pragma unroll 4
  for (int k4 = 0; k4 < 32; k4++) {
    const float* wr = W1 + (size_t)(k4 * 4) * ldW + n;
    float4 w0 = *(const float4*)(wr);
    float4 w1 = *(const float4*)(wr + ldW);
    float4 w2 = *(const float4*)(wr + 2 * (size_t)ldW);
    float4 w3 = *(const float4*)(wr + 3 * (size_t)ldW);
    #pragma unroll
    for (int r = 0; r < 4; r++) {
      float4 a = *(const float4*)&As[(ty + r * 8) * 128 + k4 * 4];
      acc[r][0] += a.x*w0.x + a.y*w1.x + a.z*w2.x + a.w*w3.x;
      acc[r][1] += a.x*w0.y + a.y*w1.y + a.z*w2.y + a.w*w3.y;
      acc[r][2] += a.x*w0.z + a.y*w1.z + a.z*w2.z + a.w*w3.z;
      acc[r][3] += a.x*w0.w + a.y*w1.w + a.z*w2.w + a.w*w3.w;
    }
  }
  if (HASB) {
    #pragma unroll 4
    for (int k4 = 0; k4 < 32; k4++) {
      const float* wr = W2 + (size_t)(k4 * 4) * ldW + n;
      float4 w0 = *(const float4*)(wr);
      float4 w1 = *(const float4*)(wr + ldW);
      float4 w2 = *(const float4*)(wr + 2 * (size_t)ldW);
      float4 w3 = *(const float4*)(wr + 3 * (size_t)ldW);
      #pragma unroll
      for (int r = 0; r < 4; r++) {
        float4 a = *(const float4*)&Bs[(ty + r * 8) * 128 + k4 * 4];
        acc[r][0] += a.x*w0.x + a.y*w1.x + a.z*w2.x + a.w*w3.x;
        acc[r][1] += a.x*w0.y + a.y*w1.y + a.z*w2.y + a.w*w3.y;
        acc[r][2] += a.x*w0.z + a.y*w1.z + a.z*w2.z + a.w*w3.z;
        acc[r][3] += a.x*w0.w + a.y*w1.w + a.z*w2.w + a.w*w3.w;
      }
    }
  }
  float4 bv = make_float4(0.f, 0.f, 0.f, 0.f);
  if (bias) bv = *(const float4*)&bias[n];
  #pragma unroll
  for (int r = 0; r < 4; r++) {
    int m = m0 + ty + r * 8;
    float4 o;
    o.x = acc[r][0] + bv.x; o.y = acc[r][1] + bv.y;
    o.z = acc[r][2] + bv.z; o.w = acc[r][3] + bv.w;
    if (RELU) {
      o.x = fmaxf(o.x, 0.f); o.y = fmaxf(o.y, 0.f);
      o.z = fmaxf(o.z, 0.f); o.w = fmaxf(o.w, 0.f);
    }
    if (HASRES) {
      float4 rr = *(const float4*)&Res[(size_t)m * ldOut + n];
      o.x += rr.x; o.y += rr.y; o.z += rr.z; o.w += rr.w;
    }
    *(float4*)&out[(size_t)m * ldOut + n] = o;
  }
}

// ---------------- fused msg pair: outA = A@Wtop ; outB = A@Wbot + bias ------
__global__ __launch_bounds__(256) void msg2_kernel(
    const float* __restrict__ A, const float* __restrict__ Wtop,
    const float* __restrict__ Wbot, const float* __restrict__ bias,
    float* __restrict__ outA, float* __restrict__ outB) {
  __shared__ float As[32 * 128];
  const int m0 = blockIdx.x * 32;
  {
    const float4* Ap = (const float4*)(A + (size_t)m0 * 128);
    #pragma unroll
    for (int t = 0; t < 4; t++) {
      int idx = threadIdx.x + 256 * t;
      ((float4*)As)[idx] = Ap[idx];
    }
  }
  __syncthreads();
  const int tx = threadIdx.x & 31, ty = threadIdx.x >> 5;
  const int n = tx * 4;

  #pragma unroll 1
  for (int phase = 0; phase < 2; phase++) {
    const float* W = phase ? Wbot : Wtop;
    float acc[4][4];
    #pragma unroll
    for (int r = 0; r < 4; r++)
      #pragma unroll
      for (int j = 0; j < 4; j++) acc[r][j] = 0.f;
    #pragma unroll 4
    for (int k4 = 0; k4 < 32; k4++) {
      const float* wr = W + (size_t)(k4 * 4) * HID + n;
      float4 w0 = *(const float4*)(wr);
      float4 w1 = *(const float4*)(wr + HID);
      float4 w2 = *(const float4*)(wr + 2 * HID);
      float4 w3 = *(const float4*)(wr + 3 * HID);
      #pragma unroll
      for (int r = 0; r < 4; r++) {
        float4 a = *(const float4*)&As[(ty + r * 8) * 128 + k4 * 4];
        acc[r][0] += a.x*w0.x + a.y*w1.x + a.z*w2.x + a.w*w3.x;
        acc[r][1] += a.x*w0.y + a.y*w1.y + a.z*w2.y + a.w*w3.y;
        acc[r][2] += a.x*w0.z + a.y*w1.z + a.z*w2.z + a.w*w3.z;
        acc[r][3] += a.x*w0.w + a.y*w1.w + a.z*w2.w + a.w*w3.w;
      }
    }
    float4 bv = make_float4(0.f, 0.f, 0.f, 0.f);
    if (phase) bv = *(const float4*)&bias[n];
    float* out = phase ? outB : outA;
    #pragma unroll
    for (int r = 0; r < 4; r++) {
      int m = m0 + ty + r * 8;
      float4 o;
      o.x = acc[r][0] + bv.x; o.y = acc[r][1] + bv.y;
      o.z = acc[r][2] + bv.z; o.w = acc[r][3] + bv.w;
      *(float4*)&out[(size_t)m * HID + n] = o;
    }
  }
}

// ---------------- fused message + mean-aggregation ----------------
__global__ __launch_bounds__(128) void agg_kernel(const float* __restrict__ Abuf,
                                                  const float* __restrict__ Bbuf,
                                                  const int* __restrict__ row_ptr,
                                                  const int* __restrict__ col,
                                                  float* __restrict__ agg) {
  int j = blockIdx.x;
  int c = threadIdx.x;
  float bj = Bbuf[(size_t)j * HID + c];
  int s = row_ptr[j], e = row_ptr[j + 1];
  float acc = 0.f;
  int p = s;
  for (; p + 4 <= e; p += 4) {
    int i0 = col[p], i1 = col[p+1], i2 = col[p+2], i3 = col[p+3];
    float v0 = Abuf[(size_t)i0 * HID + c];
    float v1 = Abuf[(size_t)i1 * HID + c];
    float v2 = Abuf[(size_t)i2 * HID + c];
    float v3 = Abuf[(size_t)i3 * HID + c];
    acc += fmaxf(v0 + bj, 0.f) + fmaxf(v1 + bj, 0.f)
         + fmaxf(v2 + bj, 0.f) + fmaxf(v3 + bj, 0.f);
  }
  for (; p < e; p++) {
    int i = col[p];
    acc += fmaxf(Abuf[(size_t)i * HID + c] + bj, 0.f);
  }
  float deg = (float)(e - s);
  float inv = 1.0f / fmaxf(deg, 1.0f);
  agg[(size_t)j * HID + c] = acc * inv;
}

extern "C" void kernel_launch(void* const* d_in, const int* in_sizes, int n_in,
                              void* d_out, int out_size, void* d_ws, size_t ws_size,
                              hipStream_t stream) {
  (void)in_sizes; (void)n_in; (void)out_size; (void)ws_size;
  const float* x       = (const float*)d_in[0];
  const float* pos     = (const float*)d_in[1];
  const float* enc_w0  = (const float*)d_in[3];
  const float* enc_b0  = (const float*)d_in[4];
  const float* enc_w1  = (const float*)d_in[5];
  const float* enc_b1  = (const float*)d_in[6];
  const float* msg_w   = (const float*)d_in[7];
  const float* msg_b   = (const float*)d_in[8];
  const float* upd_w   = (const float*)d_in[9];
  const float* upd_b   = (const float*)d_in[10];
  const float* proj_w0 = (const float*)d_in[11];
  const float* proj_b0 = (const float*)d_in[12];
  const float* proj_w1 = (const float*)d_in[13];
  const float* proj_b1 = (const float*)d_in[14];

  char* ws = (char*)d_ws;
  size_t off = 0;
  auto alloc = [&](size_t bytes) -> void* {
    void* p = ws + off;
    off += (bytes + 255) & ~(size_t)255;
    return p;
  };
  int*   nbr     = (int*)alloc((size_t)EE * 4);
  int*   cnt     = (int*)alloc((size_t)BN * 4);
  int*   fill    = (int*)alloc((size_t)BN * 4);
  int*   row_ptr = (int*)alloc((size_t)(BN + 1) * 4);
  int*   col     = (int*)alloc((size_t)EE * 4);
  float* h_a     = (float*)alloc((size_t)BN * HID * 4);
  float* h_b     = (float*)alloc((size_t)BN * HID * 4);
  float* bufA    = (float*)alloc((size_t)BN * HID * 4);
  float* bufB    = (float*)alloc((size_t)BN * HID * 4);
  float* bufAgg  = (float*)alloc((size_t)BN * HID * 4);
  float* out     = (float*)d_out;
  float* hOut    = out + (size_t)BN * PROJ_D;   // final h written here directly

  // cnt and fill are contiguous -> one memset
  hipMemsetAsync(cnt, 0, (size_t)BN * 4 * 2, stream);

  knn_kernel<<<BN / QPB, 1024, 0, stream>>>(pos, nbr);
  count_kernel<<<EE / 256, 256, 0, stream>>>(nbr, cnt);
  scan_kernel<<<1, 256, 0, stream>>>(cnt, row_ptr);
  fill_kernel<<<EE / 256, 256, 0, stream>>>(nbr, row_ptr, fill, col);

  enc0_kernel<<<BN * 32 / 256, 256, 0, stream>>>(x, enc_w0, enc_b0, bufA);
  gemm32<0,1,0><<<dim3(BN / 32, 1), 256, 0, stream>>>(
      bufA, enc_w1, nullptr, nullptr, enc_b1, nullptr, h_a, HID, HID);

  float* hc = h_a;
  float* hn = h_b;
  for (int i = 0; i < 3; i++) {
    const float* Wm = msg_w + (size_t)i * 256 * HID;
    msg2_kernel<<<BN / 32, 256, 0, stream>>>(
        hc, Wm, Wm + 128 * HID, msg_b + (size_t)i * HID, bufA, bufB);
    agg_kernel<<<BN, 128, 0, stream>>>(bufA, bufB, row_ptr, col, bufAgg);
    const float* Wu = upd_w + (size_t)i * 256 * HID;
    float* target = (i == 2) ? hOut : hn;
    gemm32<1,1,1><<<dim3(BN / 32, 1), 256, 0, stream>>>(
        hc, Wu, bufAgg, Wu + 128 * HID, upd_b + (size_t)i * HID, hc, target, HID, HID);
    hn = hc; hc = target;
  }

  gemm32<0,1,0><<<dim3(BN / 32, 1), 256, 0, stream>>>(
      hc, proj_w0, nullptr, nullptr, proj_b0, nullptr, bufA, HID, HID);
  gemm32<0,0,0><<<dim3(BN / 32, 2), 256, 0, stream>>>(
      bufA, proj_w1, nullptr, nullptr, proj_b1, nullptr, out, PROJ_D, PROJ_D);
}

// Round 5
// 326.239 us; speedup vs baseline: 2.2668x; 1.4233x over previous
//
#include <hip/hip_runtime.h>
#include <stdint.h>
#include <math.h>

#define NN 2048
#define BB 8
#define BN (BB*NN)
#define KK 16
#define EE (BN*KK)
#define HID 128
#define PROJ_D 256
#define QPB 16   // queries (waves) per knn block

typedef unsigned long long u64;

__device__ __forceinline__ u64 wave_min_u64(u64 v) {
  #pragma unroll
  for (int off = 32; off > 0; off >>= 1) {
    u64 o = __shfl_xor(v, off);
    v = o < v ? o : v;
  }
  return v;
}

// ---------------- kNN: 16 waves per block, one query per wave ----------------
// Histogram selection (exact): edge ORDER is irrelevant downstream (CSR sum),
// only the exact top-17 SET with reference tie-break (dist_bits, then index).
// key = (dist_bits << 11) | j  -- unique, 43 bits, matches top_k semantics.
__global__ __launch_bounds__(1024) void knn_kernel(const float* __restrict__ pos,
                                                   int* __restrict__ nbr) {
  __shared__ float4 Ps[NN];            // 32 KB
  __shared__ unsigned Hist[QPB * 256]; // 16 KB, private 256 bins per wave
  const int b  = blockIdx.x >> 7;          // / (NN/QPB) = /128
  const int qb = blockIdx.x & 127;
  const int wave = threadIdx.x >> 6;
  const int lane = threadIdx.x & 63;
  const int i = qb * QPB + wave;           // query index within batch
  const float* P = pos + (size_t)b * NN * 3;

  for (int t = threadIdx.x; t < NN; t += 1024)
    Ps[t] = make_float4(P[t*3], P[t*3+1], P[t*3+2], 0.f);

  unsigned* H = &Hist[wave * 256];
  *(uint4*)&H[lane * 4] = make_uint4(0u, 0u, 0u, 0u);
  __syncthreads();   // Ps staged + hist zeroed (all waves uniform path)

  const float4 pi = Ps[i];
  const float xi = pi.x, yi = pi.y, zi = pi.z;

  // ---- pass 1: distances (exact reference arithmetic) + histogram ----
  float d[32];
  #pragma unroll
  for (int t = 0; t < 32; t++) {
    int j = t * 64 + lane;
    float4 pj = Ps[j];
    float dx = fabsf(xi - pj.x);
    float dy = fabsf(yi - pj.y);
    float dz = fabsf(zi - pj.z);
    if (dx > 0.5f) dx = 1.0f - dx;
    if (dy > 0.5f) dy = 1.0f - dy;
    if (dz > 0.5f) dz = 1.0f - dz;
    // match numpy fp32 exactly: no FMA contraction, sum order ((x+y)+z)+eps
    float s = __fadd_rn(__fadd_rn(__fadd_rn(__fmul_rn(dx,dx), __fmul_rn(dy,dy)),
                                  __fmul_rn(dz,dz)), 1e-12f);
    d[t] = __fsqrt_rn(s);
    int bin = (int)(d[t] * 256.0f);      // monotone in d
    atomicAdd(&H[bin], 1u);
  }
  __syncthreads();   // all waves did exactly 32 iters -> uniform barrier

  // ---- find bin containing rank 17 (cumulative crossing) ----
  uint4 cv = *(const uint4*)&H[lane * 4];
  unsigned s4 = cv.x + cv.y + cv.z + cv.w;
  unsigned incl = s4;
  #pragma unroll
  for (int off = 1; off < 64; off <<= 1) {
    unsigned v = __shfl_up(incl, off);
    if (lane >= off) incl += v;
  }
  unsigned base = incl - s4;
  bool has = (incl >= 17u) && (base < 17u);   // exactly one lane
  u64 hmask = __ballot(has);
  int srcl = __ffsll((unsigned long long)hmask) - 1;
  int bstar = 0; unsigned C = 0;
  if (has) {
    if (base + cv.x >= 17u)                    { bstar = lane*4 + 0; C = base; }
    else if (base + cv.x + cv.y >= 17u)        { bstar = lane*4 + 1; C = base + cv.x; }
    else if (base + cv.x + cv.y + cv.z >= 17u) { bstar = lane*4 + 2; C = base + cv.x + cv.y; }
    else                                       { bstar = lane*4 + 3; C = base + cv.x + cv.y + cv.z; }
  }
  bstar = __shfl(bstar, srcl);
  C     = __shfl(C, srcl);
  const int m = 17 - (int)C;                   // 1..17 members needed from bin bstar

  // ---- per-lane sorted list (6 slots) of this lane's members of bin bstar ----
  u64 lst[6];
  #pragma unroll
  for (int t = 0; t < 6; t++) lst[t] = ~0ull;
  #pragma unroll
  for (int t = 0; t < 32; t++) {
    int bin = (int)(d[t] * 256.0f);
    u64 key = ((u64)__float_as_uint(d[t]) << 11) | (unsigned)(t * 64 + lane);
    u64 cand = (bin == bstar) ? key : ~0ull;
    if (cand < lst[5]) {
      lst[5] = cand;
      #pragma unroll
      for (int u = 5; u > 0; u--) {
        u64 a = lst[u-1], c2 = lst[u];
        lst[u-1] = a < c2 ? a : c2;
        lst[u]   = a < c2 ? c2 : a;
      }
    }
  }

  // ---- extract m smallest keys within bin bstar; kstar = 17th overall ----
  u64 kstar = 0;
  #pragma unroll 1
  for (int r = 0; r < m; r++) {
    u64 h0 = lst[0];
    u64 gm = wave_min_u64(h0);
    kstar = gm;
    bool win = (h0 == gm);
    #pragma unroll
    for (int u = 0; u < 5; u++) lst[u] = win ? lst[u+1] : lst[u];
    lst[5] = win ? ~0ull : lst[5];
  }

  // ---- emission: all keys <= kstar, excluding self; ballot compaction ----
  int* outp = nbr + ((size_t)b * NN + i) * KK;
  int total = 0;
  #pragma unroll
  for (int t = 0; t < 32; t++) {
    int j = t * 64 + lane;
    u64 key = ((u64)__float_as_uint(d[t]) << 11) | (unsigned)j;
    bool pred = (key <= kstar) && (j != i);
    u64 msk = __ballot(pred);
    if (pred) {
      int ofs = total + __popcll(msk & ((1ull << lane) - 1ull));
      outp[ofs] = b * NN + j;
    }
    total += __popcll(msk);
  }
}

// ---------------- CSR build ----------------
__global__ __launch_bounds__(256) void count_kernel(const int* __restrict__ nbr,
                                                    int* __restrict__ cnt) {
  int e = blockIdx.x * 256 + threadIdx.x;
  atomicAdd(&cnt[nbr[e]], 1);
}

__global__ __launch_bounds__(256) void scan_kernel(const int* __restrict__ cnt,
                                                   int* __restrict__ row_ptr) {
  __shared__ int ps[256];
  int t = threadIdx.x;
  int base = t * 64;
  int s = 0;
  for (int i = 0; i < 64; i++) s += cnt[base + i];
  ps[t] = s;
  __syncthreads();
  for (int off = 1; off < 256; off <<= 1) {
    int v = 0;
    if (t >= off) v = ps[t - off];
    __syncthreads();
    ps[t] += v;
    __syncthreads();
  }
  int run = t ? ps[t - 1] : 0;
  for (int i = 0; i < 64; i++) { row_ptr[base + i] = run; run += cnt[base + i]; }
  if (t == 255) row_ptr[BN] = run;
}

__global__ __launch_bounds__(256) void fill_kernel(const int* __restrict__ nbr,
                                                   const int* __restrict__ row_ptr,
                                                   int* __restrict__ fill,
                                                   int* __restrict__ col) {
  int e = blockIdx.x * 256 + threadIdx.x;
  int d = nbr[e];
  int srcn = e >> 4;                  // / KK
  int p = row_ptr[d] + atomicAdd(&fill[d], 1);
  col[p] = srcn;
}

// ---------------- encoder layer 0: (BN,5)@(5,128)+relu ----------------
__global__ __launch_bounds__(256) void enc0_kernel(const float* __restrict__ x,
                                                   const float* __restrict__ w0,
                                                   const float* __restrict__ b0,
                                                   float* __restrict__ h) {
  int t = blockIdx.x * 256 + threadIdx.x;
  int m = t >> 5;
  int c = (t & 31) * 4;
  float xv[5];
  #pragma unroll
  for (int d = 0; d < 5; d++) xv[d] = x[m * 5 + d];
  float4 acc = *(const float4*)&b0[c];
  #pragma unroll
  for (int d = 0; d < 5; d++) {
    float4 w = *(const float4*)&w0[d * HID + c];
    acc.x += xv[d] * w.x; acc.y += xv[d] * w.y;
    acc.z += xv[d] * w.z; acc.w += xv[d] * w.w;
  }
  acc.x = fmaxf(acc.x, 0.f); acc.y = fmaxf(acc.y, 0.f);
  acc.z = fmaxf(acc.z, 0.f); acc.w = fmaxf(acc.w, 0.f);
  *(float4*)&h[(size_t)m * HID + c] = acc;
}

// ---------------- W-in-LDS GEMM -------------------------------------------
// out[m0:m0+32, n0:n0+128] = act( A1@W1 [+ A2@W2] + bias ) [+ Res]
// The full 128x128 W slice lives in LDS; inner loop touches ONLY LDS + regs,
// so no global-latency stalls in the FMA stream (round-4 fix: msg2 was 11%
// VALUBusy waiting on global W loads).  LDS = 64K (Ws) + 16K (As) = 80 KB
// -> 2 blocks/CU, 16 waves/CU.  TWOPH: accumulate A2@W2 with a W re-stage.
template<int TWOPH, int RELU, int HASRES>
__global__ __launch_bounds__(256) void gemmW(
    const float* __restrict__ A1, const float* __restrict__ W1,
    const float* __restrict__ A2, const float* __restrict__ W2,
    const float* __restrict__ bias, const float* __restrict__ Res,
    float* __restrict__ out, int ldW, int ldOut) {
  __shared__ float Ws[128 * 128];
  __shared__ float As[32 * 128];
  const int m0 = blockIdx.x * 32;
  const int n0 = blockIdx.y * 128;
  const int tid = threadIdx.x;
  const int tx = tid & 31, ty = tid >> 5;

  float acc[4][4];
  #pragma unroll
  for (int r = 0; r < 4; r++)
    #pragma unroll
    for (int j = 0; j < 4; j++) acc[r][j] = 0.f;

  #pragma unroll 1
  for (int ph = 0; ph < (TWOPH ? 2 : 1); ph++) {
    const float* Ap = ph ? A2 : A1;
    const float* Wp = ph ? W2 : W1;
    if (ph) __syncthreads();           // all reads of Ws/As from phase 0 done
    // stage W tile [128 x 128] (cols n0..n0+127 of Wp, row stride ldW)
    {
      int row = tid >> 5, c4 = tid & 31;
      #pragma unroll
      for (int it = 0; it < 16; it++) {
        ((float4*)Ws)[tid + it * 256] =
            *(const float4*)&Wp[(size_t)(row + it * 8) * ldW + n0 + c4 * 4];
      }
    }
    // stage A tile [32 x 128]
    {
      const float4* Apv = (const float4*)(Ap + (size_t)m0 * 128);
      #pragma unroll
      for (int it = 0; it < 4; it++)
        ((float4*)As)[tid + it * 256] = Apv[tid + it * 256];
    }
    __syncthreads();

    #pragma unroll 4
    for (int k4 = 0; k4 < 32; k4++) {
      float4 w0 = ((const float4*)Ws)[(k4 * 4 + 0) * 32 + tx];
      float4 w1 = ((const float4*)Ws)[(k4 * 4 + 1) * 32 + tx];
      float4 w2 = ((const float4*)Ws)[(k4 * 4 + 2) * 32 + tx];
      float4 w3 = ((const float4*)Ws)[(k4 * 4 + 3) * 32 + tx];
      #pragma unroll
      for (int r = 0; r < 4; r++) {
        float4 a = ((const float4*)As)[(ty + r * 8) * 32 + k4];
        acc[r][0] += a.x*w0.x + a.y*w1.x + a.z*w2.x + a.w*w3.x;
        acc[r][1] += a.x*w0.y + a.y*w1.y + a.z*w2.y + a.w*w3.y;
        acc[r][2] += a.x*w0.z + a.y*w1.z + a.z*w2.z + a.w*w3.z;
        acc[r][3] += a.x*w0.w + a.y*w1.w + a.z*w2.w + a.w*w3.w;
      }
    }
  }

  const int n = n0 + tx * 4;
  float4 bv = make_float4(0.f, 0.f, 0.f, 0.f);
  if (bias) bv = *(const float4*)&bias[n];
  #pragma unroll
  for (int r = 0; r < 4; r++) {
    int m = m0 + ty + r * 8;
    float4 o;
    o.x = acc[r][0] + bv.x; o.y = acc[r][1] + bv.y;
    o.z = acc[r][2] + bv.z; o.w = acc[r][3] + bv.w;
    if (RELU) {
      o.x = fmaxf(o.x, 0.f); o.y = fmaxf(o.y, 0.f);
      o.z = fmaxf(o.z, 0.f); o.w = fmaxf(o.w, 0.f);
    }
    if (HASRES) {
      float4 rr = *(const float4*)&Res[(size_t)m * ldOut + n];
      o.x += rr.x; o.y += rr.y; o.z += rr.z; o.w += rr.w;
    }
    *(float4*)&out[(size_t)m * ldOut + n] = o;
  }
}

// ---------------- fused message + mean-aggregation ----------------
// agg[j] = inv_deg(j) * sum_{i in in(j)} relu(A[i] + B[j])   (B already has bias)
__global__ __launch_bounds__(128) void agg_kernel(const float* __restrict__ Abuf,
                                                  const float* __restrict__ Bbuf,
                                                  const int* __restrict__ row_ptr,
                                                  const int* __restrict__ col,
                                                  float* __restrict__ agg) {
  int j = blockIdx.x;
  int c = threadIdx.x;
  float bj = Bbuf[(size_t)j * HID + c];
  int s = row_ptr[j], e = row_ptr[j + 1];
  float acc = 0.f;
  int p = s;
  for (; p + 4 <= e; p += 4) {
    int i0 = col[p], i1 = col[p+1], i2 = col[p+2], i3 = col[p+3];
    float v0 = Abuf[(size_t)i0 * HID + c];
    float v1 = Abuf[(size_t)i1 * HID + c];
    float v2 = Abuf[(size_t)i2 * HID + c];
    float v3 = Abuf[(size_t)i3 * HID + c];
    acc += fmaxf(v0 + bj, 0.f) + fmaxf(v1 + bj, 0.f)
         + fmaxf(v2 + bj, 0.f) + fmaxf(v3 + bj, 0.f);
  }
  for (; p < e; p++) {
    int i = col[p];
    acc += fmaxf(Abuf[(size_t)i * HID + c] + bj, 0.f);
  }
  float deg = (float)(e - s);
  float inv = 1.0f / fmaxf(deg, 1.0f);
  agg[(size_t)j * HID + c] = acc * inv;
}

extern "C" void kernel_launch(void* const* d_in, const int* in_sizes, int n_in,
                              void* d_out, int out_size, void* d_ws, size_t ws_size,
                              hipStream_t stream) {
  (void)in_sizes; (void)n_in; (void)out_size; (void)ws_size;
  const float* x       = (const float*)d_in[0];
  const float* pos     = (const float*)d_in[1];
  const float* enc_w0  = (const float*)d_in[3];
  const float* enc_b0  = (const float*)d_in[4];
  const float* enc_w1  = (const float*)d_in[5];
  const float* enc_b1  = (const float*)d_in[6];
  const float* msg_w   = (const float*)d_in[7];
  const float* msg_b   = (const float*)d_in[8];
  const float* upd_w   = (const float*)d_in[9];
  const float* upd_b   = (const float*)d_in[10];
  const float* proj_w0 = (const float*)d_in[11];
  const float* proj_b0 = (const float*)d_in[12];
  const float* proj_w1 = (const float*)d_in[13];
  const float* proj_b1 = (const float*)d_in[14];

  char* ws = (char*)d_ws;
  size_t off = 0;
  auto alloc = [&](size_t bytes) -> void* {
    void* p = ws + off;
    off += (bytes + 255) & ~(size_t)255;
    return p;
  };
  int*   nbr     = (int*)alloc((size_t)EE * 4);
  int*   cnt     = (int*)alloc((size_t)BN * 4);
  int*   fill    = (int*)alloc((size_t)BN * 4);
  int*   row_ptr = (int*)alloc((size_t)(BN + 1) * 4);
  int*   col     = (int*)alloc((size_t)EE * 4);
  float* h_a     = (float*)alloc((size_t)BN * HID * 4);
  float* h_b     = (float*)alloc((size_t)BN * HID * 4);
  float* bufA    = (float*)alloc((size_t)BN * HID * 4);
  float* bufB    = (float*)alloc((size_t)BN * HID * 4);
  float* bufAgg  = (float*)alloc((size_t)BN * HID * 4);
  float* out     = (float*)d_out;
  float* hOut    = out + (size_t)BN * PROJ_D;   // final h written here directly

  // cnt and fill are contiguous -> one memset
  hipMemsetAsync(cnt, 0, (size_t)BN * 4 * 2, stream);

  knn_kernel<<<BN / QPB, 1024, 0, stream>>>(pos, nbr);
  count_kernel<<<EE / 256, 256, 0, stream>>>(nbr, cnt);
  scan_kernel<<<1, 256, 0, stream>>>(cnt, row_ptr);
  fill_kernel<<<EE / 256, 256, 0, stream>>>(nbr, row_ptr, fill, col);

  enc0_kernel<<<BN * 32 / 256, 256, 0, stream>>>(x, enc_w0, enc_b0, bufA);
  gemmW<0,1,0><<<dim3(BN / 32, 1), 256, 0, stream>>>(
      bufA, enc_w1, nullptr, nullptr, enc_b1, nullptr, h_a, HID, HID);

  float* hc = h_a;
  float* hn = h_b;
  for (int i = 0; i < 3; i++) {
    const float* Wm = msg_w + (size_t)i * 256 * HID;
    gemmW<0,0,0><<<dim3(BN / 32, 1), 256, 0, stream>>>(
        hc, Wm, nullptr, nullptr, nullptr, nullptr, bufA, HID, HID);
    gemmW<0,0,0><<<dim3(BN / 32, 1), 256, 0, stream>>>(
        hc, Wm + 128 * HID, nullptr, nullptr, msg_b + (size_t)i * HID, nullptr,
        bufB, HID, HID);
    agg_kernel<<<BN, 128, 0, stream>>>(bufA, bufB, row_ptr, col, bufAgg);
    const float* Wu = upd_w + (size_t)i * 256 * HID;
    float* target = (i == 2) ? hOut : hn;
    gemmW<1,1,1><<<dim3(BN / 32, 1), 256, 0, stream>>>(
        hc, Wu, bufAgg, Wu + 128 * HID, upd_b + (size_t)i * HID, hc, target, HID, HID);
    hn = hc; hc = target;
  }

  gemmW<0,1,0><<<dim3(BN / 32, 1), 256, 0, stream>>>(
      hc, proj_w0, nullptr, nullptr, proj_b0, nullptr, bufA, HID, HID);
  gemmW<0,0,0><<<dim3(BN / 32, 2), 256, 0, stream>>>(
      bufA, proj_w1, nullptr, nullptr, proj_b1, nullptr, out, PROJ_D, PROJ_D);
}